// Round 1
// baseline (283.184 us; speedup 1.0000x reference)
//
#include <hip/hip_runtime.h>

constexpr int B = 64;
constexpr int N = 1024;
constexpr int F = 64;

// Output layout (flat float32, return order): mx, nodes_out, adj, weights, num_nodes+1
constexpr size_t OFF_MX    = 0;
constexpr size_t OFF_NODES = OFF_MX + (size_t)B * F;          // 4096
constexpr size_t OFF_ADJ   = OFF_NODES + (size_t)B * N * F;   // 4,198,400
constexpr size_t OFF_WTS   = OFF_ADJ + (size_t)B * N * N;     // 71,307,264
constexpr size_t OFF_NN    = OFF_WTS + (size_t)B * N * N;     // 138,416,128

// ---------------------------------------------------------------------------
// Kernel 1: mx = tanh((adj_eff[b,nn,:] . nodes_in[b]) @ W), plus num_nodes+1.
// One block per batch, 256 threads = 4 wave-groups of 64 lanes.
// ---------------------------------------------------------------------------
__global__ __launch_bounds__(256) void mx_kernel(
    const float* __restrict__ adj, const float* __restrict__ nodes,
    const float* __restrict__ x, const float* __restrict__ W,
    const int* __restrict__ num_nodes,
    float* __restrict__ out_mx, float* __restrict__ out_nn)
{
    __shared__ float a_row[N];        // adj row, 4 KB
    __shared__ float partial[4][F];   // per-group partial sums

    const int b = blockIdx.x;
    const int nn0 = num_nodes[b];
    const bool of = (nn0 + 1) > N;    // provably false for setup_inputs, kept for generality
    const int nn = of ? nn0 - 1 : nn0;

    const size_t abase = (size_t)b * N * N;
    // Load effective adj row nn into LDS
    for (int j = (int)threadIdx.x; j < N; j += 256) {
        float v;
        if (!of) {
            v = adj[abase + (size_t)nn * N + j];
        } else {
            v = (nn == N - 1 || j == N - 1) ? 0.f
                : adj[abase + (size_t)(nn + 1) * N + (j + 1)];
        }
        a_row[j] = v;
    }
    __syncthreads();

    const int f = threadIdx.x & 63;
    const int g = threadIdx.x >> 6;
    const size_t nbase = (size_t)b * N * F;

    float acc = 0.f;
    const int j0 = g * (N / 4), j1 = j0 + (N / 4);
#pragma unroll 4
    for (int j = j0; j < j1; ++j) {
        float nv;
        if (j == nn) {
            nv = x[b * F + f];
        } else if (of) {
            nv = (j == N - 1) ? 0.f : nodes[nbase + (size_t)(j + 1) * F + f];
        } else {
            nv = nodes[nbase + (size_t)j * F + f];
        }
        acc += a_row[j] * nv;
    }
    partial[g][f] = acc;
    __syncthreads();

    if (threadIdx.x < F) {
        partial[0][threadIdx.x] = partial[0][threadIdx.x] + partial[1][threadIdx.x]
                                + partial[2][threadIdx.x] + partial[3][threadIdx.x];
    }
    __syncthreads();

    if (threadIdx.x < F) {
        const int fp = threadIdx.x;
        float s = 0.f;
#pragma unroll
        for (int k = 0; k < F; ++k) s += partial[0][k] * W[k * F + fp];
        out_mx[b * F + fp] = tanhf(s);
    }
    if (threadIdx.x == 0) out_nn[b] = (float)(nn + 1);
}

// ---------------------------------------------------------------------------
// Kernel 2: nodes_out = nodes_in + masked sinusoidal positional embedding.
// One float4 (4 consecutive f) per thread. B*N*F/4 = 1,048,576 threads.
// ---------------------------------------------------------------------------
__global__ __launch_bounds__(256) void nodes_out_kernel(
    const float* __restrict__ nodes, const float* __restrict__ x,
    const int* __restrict__ num_nodes, float* __restrict__ out_nodes)
{
    const int idx = blockIdx.x * 256 + threadIdx.x;
    const int total = B * N * (F / 4);
    if (idx >= total) return;

    const int f4   = idx & (F / 4 - 1);     // 0..15
    const int rest = idx >> 4;
    const int i = rest & (N - 1);
    const int b = rest >> 10;

    const int nn0 = num_nodes[b];
    const bool of = (nn0 + 1) > N;
    const int nn = of ? nn0 - 1 : nn0;
    const int f0 = f4 * 4;

    float4 v;
    if (i == nn) {
        v = *(const float4*)(x + b * F + f0);
    } else if (of) {
        v = (i == N - 1) ? make_float4(0.f, 0.f, 0.f, 0.f)
            : *(const float4*)(nodes + ((size_t)b * N + (i + 1)) * F + f0);
    } else {
        v = *(const float4*)(nodes + ((size_t)b * N + i) * F + f0);
    }

    if (i <= nn) {
        // emb[i,f] = sin(i * 10000^(-f/512))  (only the sin half survives [:, :F])
        const float C = 13.287712379549449f / 512.0f;  // log2(10000)/512
        const float fi = (float)i;
        float e[4];
#pragma unroll
        for (int k = 0; k < 4; ++k) {
            const float invf = exp2f(-C * (float)(f0 + k));
            e[k] = sinf(fi * invf);
        }
        v.x += e[0]; v.y += e[1]; v.z += e[2]; v.w += e[3];
    }
    *(float4*)(out_nodes + ((size_t)b * N + i) * F + f0) = v;
}

// ---------------------------------------------------------------------------
// Kernel 3: pass-through copy of adj and weights (with generality for the
// never-taken shift path). One row (1024 floats = 256 float4) per block
// iteration; grid-stride over 2*B*N rows. Fully coalesced float4.
// ---------------------------------------------------------------------------
__global__ __launch_bounds__(256) void copy_rows(
    const float* __restrict__ adj, const float* __restrict__ wts,
    const int* __restrict__ num_nodes,
    float* __restrict__ oadj, float* __restrict__ owts)
{
    const int total_rows = 2 * B * N;
    for (int row = blockIdx.x; row < total_rows; row += gridDim.x) {
        const bool which = row >= B * N;
        const int r = which ? row - B * N : row;
        const int b = r >> 10;          // / N
        const int i = r & (N - 1);      // % N
        const float* src = which ? wts : adj;
        float* dst = which ? owts : oadj;
        const size_t base = (size_t)b * N * N + (size_t)i * N;
        const int nn0 = num_nodes[b];
        if ((nn0 + 1) <= N) {
            const float4* s4 = (const float4*)(src + base);
            float4* d4 = (float4*)(dst + base);
            d4[threadIdx.x] = s4[threadIdx.x];
        } else {
            float* d = dst + base;
            if (i == N - 1) {
                for (int j = (int)threadIdx.x; j < N; j += 256) d[j] = 0.f;
            } else {
                const float* s = src + (size_t)b * N * N + (size_t)(i + 1) * N;
                for (int j = (int)threadIdx.x; j < N; j += 256)
                    d[j] = (j == N - 1) ? 0.f : s[j + 1];
            }
        }
    }
}

extern "C" void kernel_launch(void* const* d_in, const int* in_sizes, int n_in,
                              void* d_out, int out_size, void* d_ws, size_t ws_size,
                              hipStream_t stream)
{
    const float* x         = (const float*)d_in[0];
    const float* nodes     = (const float*)d_in[1];
    const float* adj       = (const float*)d_in[2];
    const float* wts       = (const float*)d_in[3];
    const float* W         = (const float*)d_in[4];
    const int*   num_nodes = (const int*)d_in[5];

    float* out = (float*)d_out;
    float* out_mx    = out + OFF_MX;
    float* out_nodes = out + OFF_NODES;
    float* out_adj   = out + OFF_ADJ;
    float* out_wts   = out + OFF_WTS;
    float* out_nn    = out + OFF_NN;

    hipLaunchKernelGGL(mx_kernel, dim3(B), dim3(256), 0, stream,
                       adj, nodes, x, W, num_nodes, out_mx, out_nn);

    hipLaunchKernelGGL(nodes_out_kernel, dim3((B * N * (F / 4)) / 256), dim3(256), 0, stream,
                       nodes, x, num_nodes, out_nodes);

    hipLaunchKernelGGL(copy_rows, dim3(4096), dim3(256), 0, stream,
                       adj, wts, num_nodes, out_adj, out_wts);
}

// Round 2
// 272.201 us; speedup vs baseline: 1.0403x; 1.0403x over previous
//
#include <hip/hip_runtime.h>

constexpr int B = 64;
constexpr int N = 1024;
constexpr int F = 64;

// Output layout (flat float32, return order): mx, nodes_out, adj, weights, num_nodes+1
constexpr size_t OFF_MX    = 0;
constexpr size_t OFF_NODES = OFF_MX + (size_t)B * F;          // 4096
constexpr size_t OFF_ADJ   = OFF_NODES + (size_t)B * N * F;   // 4,198,400
constexpr size_t OFF_WTS   = OFF_ADJ + (size_t)B * N * N;     // 71,307,264
constexpr size_t OFF_NN    = OFF_WTS + (size_t)B * N * N;     // 138,416,128

constexpr size_t ADJ4   = (size_t)B * N * N / 4;   // 16,777,216 float4 per matrix set
constexpr size_t COPY4  = 2 * ADJ4;                // adj + weights
constexpr size_t NODES4 = (size_t)B * N * F / 4;   // 1,048,576
constexpr size_t TOT4   = COPY4 + NODES4;

// ---------------------------------------------------------------------------
// Kernel 1: mx = tanh((adj_eff[b,nn,:] . nodes_in_eff[b]) @ W), plus nn+1.
// One block per batch, 1024 threads = 16 wave-groups (latency hiding on 64 CUs).
// ---------------------------------------------------------------------------
__global__ __launch_bounds__(1024) void mx_kernel(
    const float* __restrict__ adj, const float* __restrict__ nodes,
    const float* __restrict__ x, const float* __restrict__ W,
    const int* __restrict__ num_nodes,
    float* __restrict__ out_mx, float* __restrict__ out_nn)
{
    __shared__ float a_row[N];          // adj row, 4 KB
    __shared__ float partial[16][F];    // per-group partial sums, 4 KB

    const int b = blockIdx.x;
    const int nn0 = num_nodes[b];
    const bool of = (nn0 + 1) > N;      // false for these inputs; kept for correctness
    const int nn = of ? nn0 - 1 : nn0;

    const size_t abase = (size_t)b * N * N;
    {
        const int j = (int)threadIdx.x;   // 1024 threads cover N exactly
        float v;
        if (!of) {
            v = adj[abase + (size_t)nn * N + j];
        } else {
            v = (nn == N - 1 || j == N - 1) ? 0.f
                : adj[abase + (size_t)(nn + 1) * N + (j + 1)];
        }
        a_row[j] = v;
    }
    __syncthreads();

    const int f = threadIdx.x & 63;
    const int g = threadIdx.x >> 6;     // 0..15
    const size_t nbase = (size_t)b * N * F;

    float acc = 0.f;
    const int j0 = g * (N / 16), j1 = j0 + (N / 16);   // 64 j's per group
#pragma unroll 4
    for (int j = j0; j < j1; ++j) {
        float nv;
        if (j == nn) {
            nv = x[b * F + f];
        } else if (of) {
            nv = (j == N - 1) ? 0.f : nodes[nbase + (size_t)(j + 1) * F + f];
        } else {
            nv = nodes[nbase + (size_t)j * F + f];
        }
        acc += a_row[j] * nv;
    }
    partial[g][f] = acc;
    __syncthreads();

    if (threadIdx.x < F) {
        float s = 0.f;
#pragma unroll
        for (int g2 = 0; g2 < 16; ++g2) s += partial[g2][threadIdx.x];
        a_row[threadIdx.x] = s;          // reuse a_row[0..63] as agg vector
    }
    __syncthreads();

    if (threadIdx.x < F) {
        const int fp = threadIdx.x;
        float s = 0.f;
#pragma unroll
        for (int k = 0; k < F; ++k) s += a_row[k] * W[k * F + fp];
        out_mx[b * F + fp] = tanhf(s);
    }
    if (threadIdx.x == 0) out_nn[b] = (float)(nn + 1);
}

// ---------------------------------------------------------------------------
// Kernel 2 (fused): grid-stride over float4 units covering
//   [0, COPY4)        : adj+weights pass-through (contiguous dst in d_out)
//   [COPY4, TOT4)     : nodes_out = nodes(+x row) + masked sin embedding
// x4 unrolled so each thread keeps 4 independent loads in flight.
// ---------------------------------------------------------------------------
__device__ __forceinline__ void process_unit(
    size_t u,
    const float* __restrict__ adj, const float* __restrict__ wts,
    const float* __restrict__ nodes, const float* __restrict__ x,
    const int* __restrict__ num_nodes,
    float* __restrict__ out_copy,      // = out + OFF_ADJ
    float* __restrict__ out_nodes)     // = out + OFF_NODES
{
    if (u < COPY4) {
        const bool which = u >= ADJ4;
        const size_t k = which ? u - ADJ4 : u;
        const int b = (int)(k >> 18);                 // N*N/4 = 2^18 float4/batch
        const int nn0 = num_nodes[b];
        if (nn0 + 1 <= N) {
            const float4* src4 = (const float4*)(which ? wts : adj);
            ((float4*)out_copy)[u] = src4[k];
        } else {
            // shifted path (never taken for these inputs)
            const float* src = which ? wts : adj;
            const size_t e = k * 4;
            const int rem = (int)(e & ((size_t)N * N - 1));
            const int i = rem >> 10;
            const int j0 = rem & (N - 1);
            float* d = out_copy + u * 4;
#pragma unroll
            for (int t = 0; t < 4; ++t) {
                const int j = j0 + t;
                d[t] = (i == N - 1 || j == N - 1) ? 0.f
                     : src[(size_t)b * N * N + (size_t)(i + 1) * N + (j + 1)];
            }
        }
    } else {
        const size_t v = u - COPY4;
        const int f4 = (int)(v & (F / 4 - 1));        // 0..15
        const int i  = (int)((v >> 4) & (N - 1));
        const int b  = (int)(v >> 14);
        const int nn0 = num_nodes[b];
        const bool of = (nn0 + 1) > N;
        const int nn = of ? nn0 - 1 : nn0;
        const int f0 = f4 * 4;

        float4 val;
        if (i == nn) {
            val = *(const float4*)(x + b * F + f0);
        } else if (of) {
            val = (i == N - 1) ? make_float4(0.f, 0.f, 0.f, 0.f)
                : *(const float4*)(nodes + ((size_t)b * N + (i + 1)) * F + f0);
        } else {
            val = *(const float4*)(nodes + ((size_t)b * N + i) * F + f0);
        }

        if (i <= nn) {
            // emb[i,f] = sin(i * 10000^(-f/512)); only the sin half survives [:, :F]
            const float C = 13.287712379549449f / 512.0f;   // log2(10000)/512
            const float fi = (float)i;
            float e[4];
#pragma unroll
            for (int t = 0; t < 4; ++t) {
                const float invf = exp2f(-C * (float)(f0 + t));
                e[t] = sinf(fi * invf);
            }
            val.x += e[0]; val.y += e[1]; val.z += e[2]; val.w += e[3];
        }
        *(float4*)(out_nodes + ((size_t)b * N + i) * F + f0) = val;
    }
}

__global__ __launch_bounds__(256) void fused_kernel(
    const float* __restrict__ adj, const float* __restrict__ wts,
    const float* __restrict__ nodes, const float* __restrict__ x,
    const int* __restrict__ num_nodes,
    float* __restrict__ out_copy, float* __restrict__ out_nodes)
{
    const size_t stride = (size_t)gridDim.x * 256;
    for (size_t u0 = (size_t)blockIdx.x * 256 + threadIdx.x; u0 < TOT4; u0 += 4 * stride) {
#pragma unroll
        for (int r = 0; r < 4; ++r) {
            const size_t u = u0 + (size_t)r * stride;
            if (u < TOT4)
                process_unit(u, adj, wts, nodes, x, num_nodes, out_copy, out_nodes);
        }
    }
}

extern "C" void kernel_launch(void* const* d_in, const int* in_sizes, int n_in,
                              void* d_out, int out_size, void* d_ws, size_t ws_size,
                              hipStream_t stream)
{
    const float* x         = (const float*)d_in[0];
    const float* nodes     = (const float*)d_in[1];
    const float* adj       = (const float*)d_in[2];
    const float* wts       = (const float*)d_in[3];
    const float* W         = (const float*)d_in[4];
    const int*   num_nodes = (const int*)d_in[5];

    float* out = (float*)d_out;

    hipLaunchKernelGGL(mx_kernel, dim3(B), dim3(1024), 0, stream,
                       adj, nodes, x, W, num_nodes, out + OFF_MX, out + OFF_NN);

    hipLaunchKernelGGL(fused_kernel, dim3(2048), dim3(256), 0, stream,
                       adj, wts, nodes, x, num_nodes, out + OFF_ADJ, out + OFF_NODES);
}

// Round 4
// 185.517 us; speedup vs baseline: 1.5265x; 1.4673x over previous
//
#include <hip/hip_runtime.h>

typedef float f4 __attribute__((ext_vector_type(4)));

constexpr int B = 64;
constexpr int N = 1024;
constexpr int F = 64;

// Output layout (flat float32, return order): mx, nodes_out, adj, weights, num_nodes+1
constexpr size_t OFF_MX    = 0;
constexpr size_t OFF_NODES = OFF_MX + (size_t)B * F;          // 4096
constexpr size_t OFF_ADJ   = OFF_NODES + (size_t)B * N * F;   // 4,198,400
constexpr size_t OFF_WTS   = OFF_ADJ + (size_t)B * N * N;     // 71,307,264
constexpr size_t OFF_NN    = OFF_WTS + (size_t)B * N * N;     // 138,416,128

constexpr int THREADS = 256;

// ---- copy region geometry (adj + weights pass-through) --------------------
constexpr int    CP_UPT        = 8;                          // f4 units per thread
constexpr int    CP_UPB        = THREADS * CP_UPT;           // 2048 units per block
constexpr size_t BM_UNITS      = (size_t)N * N / 4;          // 262,144 units per (batch,matrix)
constexpr int    CP_BLK_PER_BM = (int)(BM_UNITS / CP_UPB);   // 128
constexpr int    CP_BLOCKS     = 2 * B * CP_BLK_PER_BM;      // 16,384

// ---- nodes region geometry ------------------------------------------------
constexpr size_t NODES4    = (size_t)B * N * F / 4;          // 1,048,576 units
constexpr int    ND_UPT    = 4;
constexpr int    ND_UPB    = THREADS * ND_UPT;               // 1024 units per block
constexpr int    ND_BLOCKS = (int)(NODES4 / ND_UPB);         // 1024

constexpr int MX_BLOCKS  = B;                                // 64
constexpr int CP_BLOCK0  = MX_BLOCKS;
constexpr int ND_BLOCK0  = CP_BLOCK0 + CP_BLOCKS;
constexpr int GRID       = ND_BLOCK0 + ND_BLOCKS;            // 17,472

// ---------------------------------------------------------------------------
__device__ __forceinline__ void do_mx(
    int b,
    const float* __restrict__ adj, const float* __restrict__ nodes,
    const float* __restrict__ x, const float* __restrict__ W,
    const int* __restrict__ num_nodes,
    float* __restrict__ out_mx, float* __restrict__ out_nn)
{
    __shared__ float a_row[N];          // 4 KB
    __shared__ float partial[4][F];     // 1 KB

    const int nn0 = num_nodes[b];
    const bool of = (nn0 + 1) > N;      // false for these inputs; kept for correctness
    const int nn = of ? nn0 - 1 : nn0;

    const size_t abase = (size_t)b * N * N;
    for (int j = (int)threadIdx.x; j < N; j += THREADS) {
        float v;
        if (!of) {
            v = adj[abase + (size_t)nn * N + j];
        } else {
            v = (nn == N - 1 || j == N - 1) ? 0.f
                : adj[abase + (size_t)(nn + 1) * N + (j + 1)];
        }
        a_row[j] = v;
    }
    __syncthreads();

    const int f = threadIdx.x & 63;
    const int g = threadIdx.x >> 6;     // 0..3
    const size_t nbase = (size_t)b * N * F;

    float acc = 0.f;
    const int j0 = g * (N / 4), j1 = j0 + (N / 4);
#pragma unroll 4
    for (int j = j0; j < j1; ++j) {
        float nv;
        if (j == nn) {
            nv = x[b * F + f];
        } else if (of) {
            nv = (j == N - 1) ? 0.f : nodes[nbase + (size_t)(j + 1) * F + f];
        } else {
            nv = nodes[nbase + (size_t)j * F + f];
        }
        acc += a_row[j] * nv;
    }
    partial[g][f] = acc;
    __syncthreads();

    if (threadIdx.x < F) {
        const int fp = threadIdx.x;
        a_row[fp] = partial[0][fp] + partial[1][fp] + partial[2][fp] + partial[3][fp];
    }
    __syncthreads();

    if (threadIdx.x < F) {
        const int fp = threadIdx.x;
        float s = 0.f;
#pragma unroll
        for (int k = 0; k < F; ++k) s += a_row[k] * W[k * F + fp];
        out_mx[b * F + fp] = tanhf(s);
    }
    if (threadIdx.x == 0) out_nn[b] = (float)(nn + 1);
}

// ---------------------------------------------------------------------------
__global__ __launch_bounds__(THREADS) void fused_all(
    const float* __restrict__ adj, const float* __restrict__ wts,
    const float* __restrict__ nodes, const float* __restrict__ x,
    const float* __restrict__ W, const int* __restrict__ num_nodes,
    float* __restrict__ out)
{
    const int blk = blockIdx.x;

    if (blk >= CP_BLOCK0 && blk < ND_BLOCK0) {
        // ---------------- copy region: adj + weights pass-through ----------
        const int cb = blk - CP_BLOCK0;
        const int bm = cb / CP_BLK_PER_BM;          // 0..127  (block-uniform)
        const int within = cb - bm * CP_BLK_PER_BM; // 0..127
        const bool which = bm >= B;
        const int b = which ? bm - B : bm;
        const int nn0 = num_nodes[b];

        f4* __restrict__ dst = (f4*)(out + OFF_ADJ) + (size_t)bm * BM_UNITS
                             + (size_t)within * CP_UPB + threadIdx.x;
        const f4* __restrict__ src = (const f4*)(which ? wts : adj)
                             + (size_t)b * BM_UNITS
                             + (size_t)within * CP_UPB + threadIdx.x;

        if (nn0 + 1 <= N) {
            // fast path: straight-line 8 loads -> 8 stores, no branches
            f4 v[CP_UPT];
#pragma unroll
            for (int r = 0; r < CP_UPT; ++r)
                v[r] = __builtin_nontemporal_load(src + r * THREADS);
#pragma unroll
            for (int r = 0; r < CP_UPT; ++r)
                __builtin_nontemporal_store(v[r], dst + r * THREADS);
        } else {
            // shifted path (never taken for these inputs)
            const float* s = (which ? wts : adj) + (size_t)b * N * N;
            float* d = out + OFF_ADJ + (size_t)bm * N * N;
            const size_t base_flat = (size_t)within * CP_UPB * 4;
#pragma unroll
            for (int r = 0; r < CP_UPT; ++r) {
                const size_t flat = base_flat + ((size_t)threadIdx.x + (size_t)r * THREADS) * 4;
#pragma unroll
                for (int t = 0; t < 4; ++t) {
                    const size_t fe = flat + t;
                    const int i = (int)(fe >> 10);
                    const int j = (int)(fe & (N - 1));
                    d[fe] = (i == N - 1 || j == N - 1) ? 0.f
                          : s[(size_t)(i + 1) * N + (j + 1)];
                }
            }
        }
    } else if (blk >= ND_BLOCK0) {
        // ---------------- nodes_out region ---------------------------------
        const int nb = blk - ND_BLOCK0;
        const int b = nb >> 4;                       // 16 blocks per batch
        const int nn0 = num_nodes[b];
        const bool of = (nn0 + 1) > N;
        const int nn = of ? nn0 - 1 : nn0;

        const size_t base_u = (size_t)nb * ND_UPB;   // unit = one f4 of nodes
#pragma unroll
        for (int r = 0; r < ND_UPT; ++r) {
            const size_t v = base_u + (size_t)r * THREADS + threadIdx.x;
            const int f4i = (int)(v & (F / 4 - 1));
            const int i   = (int)((v >> 4) & (N - 1));
            const int f0  = f4i * 4;

            f4 val;
            if (i == nn) {
                val = *(const f4*)(x + b * F + f0);
            } else if (of) {
                val = (f4){0.f, 0.f, 0.f, 0.f};
                if (i != N - 1)
                    val = __builtin_nontemporal_load((const f4*)(nodes + ((size_t)b * N + (i + 1)) * F + f0));
            } else {
                val = __builtin_nontemporal_load((const f4*)(nodes + ((size_t)b * N + i) * F + f0));
            }

            if (i <= nn) {
                const float C = 13.287712379549449f / 512.0f;   // log2(10000)/512
                const float fi = (float)i;
#pragma unroll
                for (int t = 0; t < 4; ++t) {
                    const float invf = exp2f(-C * (float)(f0 + t));
                    val[t] += sinf(fi * invf);
                }
            }
            __builtin_nontemporal_store(val, (f4*)(out + OFF_NODES + ((size_t)b * N + i) * F + f0));
        }
    } else {
        // ---------------- mx region (blocks 0..63) -------------------------
        do_mx(blk, adj, nodes, x, W, num_nodes, out + OFF_MX, out + OFF_NN);
    }
}

extern "C" void kernel_launch(void* const* d_in, const int* in_sizes, int n_in,
                              void* d_out, int out_size, void* d_ws, size_t ws_size,
                              hipStream_t stream)
{
    const float* x         = (const float*)d_in[0];
    const float* nodes     = (const float*)d_in[1];
    const float* adj       = (const float*)d_in[2];
    const float* wts       = (const float*)d_in[3];
    const float* W         = (const float*)d_in[4];
    const int*   num_nodes = (const int*)d_in[5];

    hipLaunchKernelGGL(fused_all, dim3(GRID), dim3(THREADS), 0, stream,
                       adj, wts, nodes, x, W, num_nodes, (float*)d_out);
}